// Round 8
// baseline (393.184 us; speedup 1.0000x reference)
//
#include <hip/hip_runtime.h>
#include <stdint.h>

typedef uint16_t u16;
typedef __bf16  bf16x8 __attribute__((ext_vector_type(8)));
typedef float   f32x4  __attribute__((ext_vector_type(4)));
typedef float   f32x16 __attribute__((ext_vector_type(16)));
typedef uint16_t u16x8 __attribute__((ext_vector_type(8), may_alias));
typedef uint32_t u32x4 __attribute__((ext_vector_type(4)));

typedef const __attribute__((address_space(1))) void* gas_p;
typedef __attribute__((address_space(3))) void* las_p;

#define SCALE2 0.1275430214486847f   // (1/sqrt(128)) * log2(e)

__device__ __forceinline__ void load_lds16(const void* g, void* l) {
    // async global->LDS DMA, 16B/lane; LDS dest = wave-uniform base + lane*16
    __builtin_amdgcn_global_load_lds((gas_p)g, (las_p)l, 16, 0, 0);
}

__device__ __forceinline__ u16 f2bf(float f) {
    uint32_t u = __builtin_bit_cast(uint32_t, f);
    u += 0x7FFFu + ((u >> 16) & 1u);   // RNE
    return (u16)(u >> 16);
}
__device__ __forceinline__ float bf2f(u16 h) {
    uint32_t u = ((uint32_t)h) << 16;
    return __builtin_bit_cast(float, u);
}
__device__ __forceinline__ bf16x8 ld_frag(const u16* p) {
    u16x8 t = *(const u16x8*)p;
    return __builtin_bit_cast(bf16x8, t);
}
__device__ __forceinline__ uint32_t cvt_pk_bf16(float lo, float hi) {
    uint32_t r;
    asm("v_cvt_pk_bf16_f32 %0, %1, %2" : "=v"(r) : "v"(lo), "v"(hi));
    return r;
}
__device__ __forceinline__ void plane32_swap(uint32_t& a, uint32_t& b) {
    // a' = {a.lo | b.lo}, b' = {a.hi | b.hi} across the lane<32 / lane>=32 split
    asm("v_permlane32_swap_b32 %0, %1" : "+v"(a), "+v"(b));
}

// ---------------------------------------------------------------- hidden convert f32 -> bf16
__global__ __launch_bounds__(256) void convert_hidden(const float* __restrict__ in,
                                                      u16* __restrict__ out, int n8) {
    int i = blockIdx.x * 256 + threadIdx.x;
    if (i >= n8) return;
    const float* p = in + (size_t)i * 8;
    u16x8 o;
#pragma unroll
    for (int j = 0; j < 8; j++) o[j] = f2bf(p[j]);
    *(u16x8*)(out + (size_t)i * 8) = o;
}

// ---------------------------------------------------------------- transpose f32 [R][C] -> bf16 [C][R]
__global__ __launch_bounds__(256) void transpose_cvt(const float* __restrict__ in,
                                                     u16* __restrict__ out,
                                                     int R, int C) {
    __shared__ u16 tile[64][65];
    const int tx = threadIdx.x;
    const int bc = blockIdx.x * 64;
    const int br = blockIdx.y * 64;
#pragma unroll
    for (int i = 0; i < 16; i++) {
        int idx = tx + i * 256;
        int r = idx >> 6, c = idx & 63;
        tile[r][c] = f2bf(in[(size_t)(br + r) * C + bc + c]);
    }
    __syncthreads();
#pragma unroll
    for (int i = 0; i < 16; i++) {
        int idx = tx + i * 256;
        int r = idx >> 6, c = idx & 63;
        out[(size_t)(bc + r) * R + br + c] = tile[c][r];
    }
}

// ---------------------------------------------------------------- transpose bf16 [R][C-slice] -> bf16 [C][R]
__global__ __launch_bounds__(256) void transpose_b16(const u16* __restrict__ in,
                                                     u16* __restrict__ out,
                                                     int R, int C, int ldin, int off) {
    __shared__ u16 tile[64][65];
    const int tx = threadIdx.x;
    const int bc = blockIdx.x * 64;
    const int br = blockIdx.y * 64;
#pragma unroll
    for (int i = 0; i < 16; i++) {
        int idx = tx + i * 256;
        int r = idx >> 6, c = idx & 63;
        tile[r][c] = in[(size_t)(br + r) * ldin + off + bc + c];
    }
    __syncthreads();
#pragma unroll
    for (int i = 0; i < 16; i++) {
        int idx = tx + i * 256;
        int r = idx >> 6, c = idx & 63;
        out[(size_t)(bc + r) * R + br + c] = tile[c][r];
    }
}

// ---------------------------------------------------------------- GEMM core (m97 style)
#define TM 128
#define TN 128
#define TK 32

// fused QKV projection: A[4096][2048] bf16; n-cols 0..2047 -> Q (WqT), 2048..3071 -> KV (WkvT)
__global__ __launch_bounds__(256) void gemm_qkv(const u16* __restrict__ A,
                                                const u16* __restrict__ WqT,
                                                const u16* __restrict__ WkvT,
                                                u16* __restrict__ Qb,
                                                u16* __restrict__ KVb) {
    __shared__ u16 As[TM * TK];
    __shared__ u16 Bs[TN * TK];
    const int K = 2048;
    const int tid  = threadIdx.x;
    const int wave = tid >> 6;
    const int lane = tid & 63;
    const int l15  = lane & 15;
    const int quad = lane >> 4;
    const int m0 = blockIdx.y * TM;
    const int n0 = blockIdx.x * TN;   // 0..2944
    const u16* Bt;
    u16* C;
    int ldC, cbase;
    if (n0 < 2048) { Bt = WqT + (size_t)n0 * K;          C = Qb;  ldC = 2048; cbase = n0; }
    else           { Bt = WkvT + (size_t)(n0 - 2048) * K; C = KVb; ldC = 1024; cbase = n0 - 2048; }
    const int wm = (wave >> 1) * 64;
    const int wn = (wave & 1) * 64;

    f32x4 acc[4][4] = {};

    const int srow = tid >> 2;
    const int scol = (tid & 3) * 8;
    const u16* Ap0 = A  + (size_t)(m0 + srow) * K + scol;
    const u16* Ap1 = A  + (size_t)(m0 + 64 + srow) * K + scol;
    const u16* Bp0 = Bt + (size_t)srow * K + scol;
    const u16* Bp1 = Bt + (size_t)(64 + srow) * K + scol;
    u16* AsD0 = As + wave * 512;
    u16* AsD1 = As + 2048 + wave * 512;
    u16* BsD0 = Bs + wave * 512;
    u16* BsD1 = Bs + 2048 + wave * 512;

    for (int k0 = 0; k0 < K; k0 += TK) {
        load_lds16(Ap0 + k0, AsD0);
        load_lds16(Ap1 + k0, AsD1);
        load_lds16(Bp0 + k0, BsD0);
        load_lds16(Bp1 + k0, BsD1);
        __syncthreads();
        bf16x8 af[4], bfr[4];
#pragma unroll
        for (int i = 0; i < 4; i++)
            af[i] = ld_frag(&As[(wm + i * 16 + l15) * TK + quad * 8]);
#pragma unroll
        for (int j = 0; j < 4; j++)
            bfr[j] = ld_frag(&Bs[(wn + j * 16 + l15) * TK + quad * 8]);
#pragma unroll
        for (int i = 0; i < 4; i++)
#pragma unroll
            for (int j = 0; j < 4; j++)
                acc[i][j] = __builtin_amdgcn_mfma_f32_16x16x32_bf16(af[i], bfr[j], acc[i][j], 0, 0, 0);
        __syncthreads();
    }
#pragma unroll
    for (int i = 0; i < 4; i++)
#pragma unroll
        for (int j = 0; j < 4; j++)
#pragma unroll
            for (int r = 0; r < 4; r++) {
                int row = m0 + wm + i * 16 + quad * 4 + r;
                int col = cbase + wn + j * 16 + l15;
                C[(size_t)row * ldC + col] = f2bf(acc[i][j][r]);
            }
}

template <bool F32OUT>
__global__ __launch_bounds__(256) void gemm_bt(const u16* __restrict__ A,
                                               const u16* __restrict__ Bt,
                                               void* __restrict__ Cp,
                                               int M, int N, int K) {
    __shared__ u16 As[TM * TK];
    __shared__ u16 Bs[TN * TK];
    const int tid  = threadIdx.x;
    const int wave = tid >> 6;
    const int lane = tid & 63;
    const int l15  = lane & 15;
    const int quad = lane >> 4;
    const int m0 = blockIdx.y * TM;
    const int n0 = blockIdx.x * TN;
    const int wm = (wave >> 1) * 64;
    const int wn = (wave & 1) * 64;

    f32x4 acc[4][4] = {};

    const int srow = tid >> 2;
    const int scol = (tid & 3) * 8;
    const u16* Ap0 = A  + (size_t)(m0 + srow) * K + scol;
    const u16* Ap1 = A  + (size_t)(m0 + 64 + srow) * K + scol;
    const u16* Bp0 = Bt + (size_t)(n0 + srow) * K + scol;
    const u16* Bp1 = Bt + (size_t)(n0 + 64 + srow) * K + scol;
    u16* AsD0 = As + wave * 512;
    u16* AsD1 = As + 2048 + wave * 512;
    u16* BsD0 = Bs + wave * 512;
    u16* BsD1 = Bs + 2048 + wave * 512;

    for (int k0 = 0; k0 < K; k0 += TK) {
        load_lds16(Ap0 + k0, AsD0);
        load_lds16(Ap1 + k0, AsD1);
        load_lds16(Bp0 + k0, BsD0);
        load_lds16(Bp1 + k0, BsD1);
        __syncthreads();
        bf16x8 af[4], bfr[4];
#pragma unroll
        for (int i = 0; i < 4; i++)
            af[i] = ld_frag(&As[(wm + i * 16 + l15) * TK + quad * 8]);
#pragma unroll
        for (int j = 0; j < 4; j++)
            bfr[j] = ld_frag(&Bs[(wn + j * 16 + l15) * TK + quad * 8]);
#pragma unroll
        for (int i = 0; i < 4; i++)
#pragma unroll
            for (int j = 0; j < 4; j++)
                acc[i][j] = __builtin_amdgcn_mfma_f32_16x16x32_bf16(af[i], bfr[j], acc[i][j], 0, 0, 0);
        __syncthreads();
    }
#pragma unroll
    for (int i = 0; i < 4; i++)
#pragma unroll
        for (int j = 0; j < 4; j++)
#pragma unroll
            for (int r = 0; r < 4; r++) {
                int row = m0 + wm + i * 16 + quad * 4 + r;
                int col = n0 + wn + j * 16 + l15;
                if (F32OUT)
                    ((float*)Cp)[(size_t)row * N + col] = acc[i][j][r];
                else
                    ((u16*)Cp)[(size_t)row * N + col] = f2bf(acc[i][j][r]);
            }
}

// ---------------------------------------------------------------- RoPE (in-place, Q + K)
// Q rows are additionally pre-scaled by SCALE2 so attention's exp2 needs no mul.
__global__ __launch_bounds__(256) void rope_kernel(u16* __restrict__ Q,
                                                   u16* __restrict__ KV) {
    int g = blockIdx.x * 256 + threadIdx.x;
    int d = g & 63;
    int row = g >> 6;
    int s = row / 20;
    int hh = row - s * 20;
    u16* buf = (hh < 16) ? (Q + (size_t)s * 2048 + hh * 128)
                         : (KV + (size_t)s * 1024 + (hh - 16) * 128);
    float p = (float)s;
    float angle = p * exp2f((float)d * (-19.931568569324174f / 64.0f));
    float sc = (hh < 16) ? SCALE2 : 1.0f;
    float c = cosf(angle) * sc, sn = sinf(angle) * sc;
    float x0 = bf2f(buf[d]), x1 = bf2f(buf[d + 64]);
    buf[d]      = f2bf(x0 * c - x1 * sn);
    buf[d + 64] = f2bf(x1 * c + x0 * sn);
}

// ---------------------------------------------------------------- flash attention compute macros
// QKSM: swapped QK^T (A=K, B=Q) for one 32-kv chunk + in-register softmax ->
//       PV A-frags (cvt_pk+permlane32_swap); fixed-reference exp2 (Q pre-scaled).
#define QKSM(CC, MSK, PA)                                                      \
  do {                                                                         \
    const int krow_ = (CC) * 32 + l31;                                         \
    f32x16 sv_ = {};                                                           \
    _Pragma("unroll")                                                          \
    for (int dk = 0; dk < 8; dk++) {                                           \
      bf16x8 kf = ld_frag(&Kb[krow_ * 128 + (((dk * 2 + hi8) + krow_) & 15) * 8]); \
      sv_ = __builtin_amdgcn_mfma_f32_32x32x16_bf16(kf, qf[dk], sv_, 0, 0, 0); \
    }                                                                          \
    float p_[16]; float rs_ = 0.f;                                             \
    const int kvbs_ = kv0 + (CC) * 32 + 4 * hi8;                               \
    _Pragma("unroll")                                                          \
    for (int r = 0; r < 16; r++) {                                             \
      float pe = exp2f(sv_[r]);                                                \
      if (MSK) { int kvv = kvbs_ + (r & 3) + 8 * (r >> 2);                     \
                 pe = (kvv <= qrow) ? pe : 0.f; }                              \
      p_[r] = pe; rs_ += pe;                                                   \
    }                                                                          \
    lr += rs_;                                                                 \
    uint32_t w0 = cvt_pk_bf16(p_[0], p_[1]);                                   \
    uint32_t w1 = cvt_pk_bf16(p_[2], p_[3]);                                   \
    uint32_t w2 = cvt_pk_bf16(p_[4], p_[5]);                                   \
    uint32_t w3 = cvt_pk_bf16(p_[6], p_[7]);                                   \
    plane32_swap(w0, w2); plane32_swap(w1, w3);                                \
    uint32_t w4 = cvt_pk_bf16(p_[8], p_[9]);                                   \
    uint32_t w5 = cvt_pk_bf16(p_[10], p_[11]);                                 \
    uint32_t w6 = cvt_pk_bf16(p_[12], p_[13]);                                 \
    plane32_swap(w4, w6);                                                      \
    uint32_t w7 = cvt_pk_bf16(p_[14], p_[15]);                                 \
    plane32_swap(w5, w7);                                                      \
    u32x4 a0_ = {w0, w1, w2, w3}, a1_ = {w4, w5, w6, w7};                      \
    PA[0] = __builtin_bit_cast(bf16x8, a0_);                                   \
    PA[1] = __builtin_bit_cast(bf16x8, a1_);                                   \
  } while (0)

// PVX: O += P*V with the V tile packed as d-PAIR rows (64 x 256B, 16 slots):
// slot s of row vr holds V^T row d=2*vr+(s>>3), kv-chunk ((s&7)-(vr&7))&7.
// Each 16B slot is read by exactly 1 lane per instruction -> conflict-free
// (v8-verified: SQ_LDS_BANK_CONFLICT -> 0).
#define PVX(CC, PA)                                                            \
  do {                                                                         \
    _Pragma("unroll")                                                          \
    for (int ks2 = 0; ks2 < 2; ks2++) {                                        \
      bf16x8 pa_ = PA[ks2];                                                    \
      _Pragma("unroll")                                                        \
      for (int nt = 0; nt < 4; nt++) {                                         \
        const int d_ = nt * 32 + l31;                                          \
        const int vr_ = d_ >> 1;                                               \
        const int s_ = (d_ & 1) * 8 + ((((CC) * 4 + ks2 * 2 + hi8) + vr_) & 7);\
        bf16x8 vf = ld_frag(&Vb[vr_ * 128 + s_ * 8]);                          \
        acc[nt] = __builtin_amdgcn_mfma_f32_32x32x16_bf16(pa_, vf, acc[nt], 0, 0, 0); \
      }                                                                        \
    }                                                                          \
  } while (0)

// legacy fused macro for the v7 fallback (linear V^T tile [128 d][64 kv])
#define QK1(CC, MSK)                                                           \
  do {                                                                         \
    const int krow_ = (CC) * 32 + l31;                                         \
    f32x16 sv_ = {};                                                           \
    _Pragma("unroll")                                                          \
    for (int dk = 0; dk < 8; dk++) {                                           \
      bf16x8 kf = ld_frag(&Kb[krow_ * 128 + (((dk * 2 + hi8) + krow_) & 15) * 8]); \
      sv_ = __builtin_amdgcn_mfma_f32_32x32x16_bf16(kf, qf[dk], sv_, 0, 0, 0); \
    }                                                                          \
    float p_[16]; float rs_ = 0.f;                                             \
    const int kvbs_ = kv0 + (CC) * 32 + 4 * hi8;                               \
    _Pragma("unroll")                                                          \
    for (int r = 0; r < 16; r++) {                                             \
      float pe = exp2f(sv_[r]);                                                \
      if (MSK) { int kvv = kvbs_ + (r & 3) + 8 * (r >> 2);                     \
                 pe = (kvv <= qrow) ? pe : 0.f; }                              \
      p_[r] = pe; rs_ += pe;                                                   \
    }                                                                          \
    lr += rs_;                                                                 \
    uint32_t w0 = cvt_pk_bf16(p_[0], p_[1]);                                   \
    uint32_t w1 = cvt_pk_bf16(p_[2], p_[3]);                                   \
    uint32_t w2 = cvt_pk_bf16(p_[4], p_[5]);                                   \
    uint32_t w3 = cvt_pk_bf16(p_[6], p_[7]);                                   \
    plane32_swap(w0, w2); plane32_swap(w1, w3);                                \
    uint32_t w4 = cvt_pk_bf16(p_[8], p_[9]);                                   \
    uint32_t w5 = cvt_pk_bf16(p_[10], p_[11]);                                 \
    uint32_t w6 = cvt_pk_bf16(p_[12], p_[13]);                                 \
    plane32_swap(w4, w6);                                                      \
    uint32_t w7 = cvt_pk_bf16(p_[14], p_[15]);                                 \
    plane32_swap(w5, w7);                                                      \
    u32x4 a0_ = {w0, w1, w2, w3}, a1_ = {w4, w5, w6, w7};                      \
    bf16x8 pa0_ = __builtin_bit_cast(bf16x8, a0_);                             \
    bf16x8 pa1_ = __builtin_bit_cast(bf16x8, a1_);                             \
    _Pragma("unroll")                                                          \
    for (int ks2 = 0; ks2 < 2; ks2++) {                                        \
      bf16x8 pa_ = ks2 ? pa1_ : pa0_;                                          \
      _Pragma("unroll")                                                        \
      for (int nt = 0; nt < 4; nt++) {                                         \
        const int d_ = nt * 32 + l31;                                          \
        bf16x8 vf = ld_frag(&Vb[d_ * 64 + ((((CC) * 4 + ks2 * 2 + hi8) + d_) & 7) * 8]); \
        acc[nt] = __builtin_amdgcn_mfma_f32_32x32x16_bf16(pa_, vf, acc[nt], 0, 0, 0); \
      }                                                                        \
    }                                                                          \
  } while (0)

// ---------------------------------------------------------------- flash attention v10 (split-kv)
// v9 structure (1024 blocks: 16h x 32 q-tiles x 2 kv-slices, heavy-first, raw
// partial O/l sums merged by merge_o) with two isolated fixes:
//  1. V d-pair LDS pack (v8-verified): kills the 4.26M 4-way V-read conflicts.
//  2. Counted split waits (T4): QK/softmax separated from PV;
//       top:    issue K(t+1)
//       mid:    issue V(t+1); vmcnt(8)+barrier  -> drains only V(t)
//       bottom: vmcnt(4)+barrier                -> drains only K(t+1)
//     V(t+1) stays in flight across the iteration boundary (never drain to 0).
__global__ __launch_bounds__(256, 2) void flash_attn10(const u16* __restrict__ Q,
                                                       const u16* __restrict__ KVb,
                                                       const u16* __restrict__ VT,
                                                       u16* __restrict__ Op0,
                                                       u16* __restrict__ Op1,
                                                       float* __restrict__ Lp) {
    __shared__ u16 Ks[2][8192];       // 2 x 16KB: K tile [64 kv][128 d], 16B chunks swizzled
    __shared__ u16 Vs[2][8192];       // 2 x 16KB: V tile as 64 d-pair rows x 16 slots
    const int tid  = threadIdx.x;
    const int ww   = tid >> 6;
    const int lane = tid & 63;
    const int l31  = lane & 31;
    const int hi8  = lane >> 5;
    const int bid  = blockIdx.x;      // 0..1023
    const int h    = (bid & 7) * 2 + ((bid >> 3) & 1);
    const int rest = bid >> 4;        // 0..63
    const int j    = 31 - (rest >> 1);
    const int s    = rest & 1;
    const int kvh  = h >> 2;
    const int qg0  = j * 128 + ww * 32;   // this wave's 32 q-rows
    const int qrow = qg0 + l31;
    const int dW   = qg0 >> 6;        // diagonal kv-block: 2j + (ww>>1)
    const int kb0  = s * (j + 1);     // slice kv range [kb0, kb1)
    const int kb1  = kb0 + (j + 1);

    // Q B-frags
    bf16x8 qf[8];
    {
        const u16* qp = Q + (size_t)qrow * 2048 + h * 128 + hi8 * 8;
#pragma unroll
        for (int dk = 0; dk < 8; dk++) qf[dk] = ld_frag(qp + dk * 16);
    }

    // DMA source pointers (4 rounds each for K and V^T)
    // K: row kv (256B), slot c stores global chunk ((c - kv) & 15).
    // V: d-pair row vr (256B), slot s stores V^T row d = 2*vr + (s>>3),
    //    kv-chunk ((s&7) - (vr&7)) & 7.
    const u16* srcK[4];
    const u16* srcV[4];
#pragma unroll
    for (int r = 0; r < 4; r++) {
        int p = r * 256 + tid;
        int kv = p >> 4;
        srcK[r] = KVb + (size_t)kv * 1024 + kvh * 128 + ((((p & 15) - kv) & 15) * 8);
        int vr = p >> 4;
        int sl = p & 15;
        int d  = 2 * vr + (sl >> 3);
        int wv = ((sl & 7) - (vr & 7)) & 7;
        srcV[r] = VT + (size_t)(kvh * 128 + d) * 4096 + wv * 8;
    }

    f32x16 acc[4] = {};               // raw O-sum [q][d = nt*32 + l31]
    float lr = 0.f;

    // prologue: stage kvb=kb0 -> buf0 (K first, then V)
#pragma unroll
    for (int r = 0; r < 4; r++)
        load_lds16(srcK[r] + (size_t)(kb0 * 64) * 1024, &Ks[0][r * 2048 + ww * 512]);
#pragma unroll
    for (int r = 0; r < 4; r++)
        load_lds16(srcV[r] + kb0 * 64, &Vs[0][r * 2048 + ww * 512]);
    asm volatile("s_waitcnt vmcnt(0)" ::: "memory");
    __syncthreads();

    for (int kvb = kb0; kvb < kb1; kvb++) {
        const int cur = (kvb - kb0) & 1;
        const bool pre = (kvb + 1 < kb1);
        const int kvn = (kvb + 1) * 64;
        // top: issue next K (writes Ks[cur^1]; last read was iter t-1's QK,
        // separated by t-1's bottom barrier)
        if (pre) {
#pragma unroll
            for (int r = 0; r < 4; r++)
                load_lds16(srcK[r] + (size_t)kvn * 1024, &Ks[cur ^ 1][r * 2048 + ww * 512]);
        }
        const u16* Kb = Ks[cur];
        const u16* Vb = Vs[cur];
        const int kv0 = kvb * 64;
        const bool act = (kvb <= dW);
        const bool msk = (kvb == dW);

        bf16x8 pa0[2], pa1[2];
        if (act) {
            if (msk) { QKSM(0, 1, pa0); QKSM(1, 1, pa1); }
            else     { QKSM(0, 0, pa0); QKSM(1, 0, pa1); }
        }

        // mid: issue next V, then drain only V(t): outstanding afterwards is
        // K(t+1)+V(t+1) = 8 (or 0 on the last iteration)
        if (pre) {
#pragma unroll
            for (int r = 0; r < 4; r++)
                load_lds16(srcV[r] + kvn, &Vs[cur ^ 1][r * 2048 + ww * 512]);
            asm volatile("s_waitcnt vmcnt(8)" ::: "memory");
        } else {
            asm volatile("s_waitcnt vmcnt(0)" ::: "memory");
        }
        __syncthreads();   // all waves' V(t) landed; PV on Vs[cur] safe

        if (act) {
            PVX(0, pa0);
            PVX(1, pa1);
        }

        // bottom: drain only K(t+1); V(t+1) stays in flight
        if (pre) {
            asm volatile("s_waitcnt vmcnt(4)" ::: "memory");
            __syncthreads();
        }
    }

    // ---- emit partials (no normalization): raw O-sums + l-sums
    float lt = lr + __shfl_xor(lr, 32);     // all lanes: l partial for q-col l31
    if (lane < 32) Lp[(s * 16 + h) * 4096 + qg0 + l31] = lt;
    u16* Ops = s ? Op1 : Op0;
#pragma unroll
    for (int r = 0; r < 16; r++) {
        int qr = (r & 3) + 8 * (r >> 2) + 4 * hi8;
        u16* op = Ops + (size_t)(qg0 + qr) * 2048 + h * 128 + l31;
#pragma unroll
        for (int nt = 0; nt < 4; nt++)
            op[nt * 32] = f2bf(acc[nt][r]);
    }
}

// ---------------------------------------------------------------- slice merge: O = (O0+O1)/(l0+l1)
// In-place into o0 (elementwise, same-thread read->write).
__global__ __launch_bounds__(256) void merge_o(u16* __restrict__ o0,
                                               const u16* __restrict__ o1,
                                               const float* __restrict__ Lp) {
    int i = blockIdx.x * 256 + threadIdx.x;       // 1,048,576 threads x 8 elems
    size_t base = (size_t)i * 8;
    int row = (int)(base >> 11);
    int h   = (int)((base >> 7) & 15);
    float inv = 1.0f / (Lp[h * 4096 + row] + Lp[(16 + h) * 4096 + row]);
    u16x8 a = *(const u16x8*)(o0 + base);
    u16x8 b = *(const u16x8*)(o1 + base);
    u16x8 o;
#pragma unroll
    for (int jj = 0; jj < 8; jj++)
        o[jj] = f2bf((bf2f(a[jj]) + bf2f(b[jj])) * inv);
    *(u16x8*)(o0 + base) = o;
}

// ---------------------------------------------------------------- flash attention v7 (fallback,
// used only when the workspace is too small for split-kv partials; 147us known-good)
__global__ __launch_bounds__(256, 2) void flash_attn7(const u16* __restrict__ Q,
                                                      const u16* __restrict__ KVb,
                                                      const u16* __restrict__ VT,
                                                      u16* __restrict__ O) {
    __shared__ u16 Ks[2][8192];
    __shared__ u16 Vs[2][8192];
    __shared__ float Llds[4][32];
    const int tid  = threadIdx.x;
    const int ww   = tid >> 6;
    const int lane = tid & 63;
    const int l31  = lane & 31;
    const int hi8  = lane >> 5;
    const int bid  = blockIdx.x;      // 0..511
    const int h    = bid >> 5;
    const int cls  = bid & 31;
    const int bx   = cls >> 1;
    const int z    = cls & 1;
    const int kvh  = h >> 2;
    const int qt0  = z ? (3968 - bx * 128) : (bx * 128);
    const int qg0  = qt0 + ww * 32;
    const int qrow = qg0 + l31;
    const int dW   = qg0 >> 6;
    const int nkv  = (qt0 >> 6) + 2;

    bf16x8 qf[8];
    {
        const u16* qp = Q + (size_t)qrow * 2048 + h * 128 + hi8 * 8;
#pragma unroll
        for (int dk = 0; dk < 8; dk++) qf[dk] = ld_frag(qp + dk * 16);
    }

    const u16* srcK[4];
    const u16* srcV[4];
#pragma unroll
    for (int r = 0; r < 4; r++) {
        int p = r * 256 + tid;
        int kv = p >> 4;
        srcK[r] = KVb + (size_t)kv * 1024 + kvh * 128 + ((((p & 15) - kv) & 15) * 8);
        int d = p >> 3;
        srcV[r] = VT + (size_t)(kvh * 128 + d) * 4096 + ((((p & 7) - (d & 7)) & 7) * 8);
    }

    f32x16 acc[4] = {};
    float lr = 0.f;

#pragma unroll
    for (int r = 0; r < 4; r++) {
        load_lds16(srcK[r], &Ks[0][r * 2048 + ww * 512]);
        load_lds16(srcV[r], &Vs[0][r * 2048 + ww * 512]);
    }
    asm volatile("s_waitcnt vmcnt(0)" ::: "memory");
    __syncthreads();

    for (int kvb = 0; kvb < nkv; kvb++) {
        const int cur = kvb & 1;
        if (kvb + 1 < nkv) {
            const int kvn = (kvb + 1) * 64;
#pragma unroll
            for (int r = 0; r < 4; r++) {
                load_lds16(srcK[r] + (size_t)kvn * 1024, &Ks[cur ^ 1][r * 2048 + ww * 512]);
                load_lds16(srcV[r] + kvn, &Vs[cur ^ 1][r * 2048 + ww * 512]);
            }
        }
        const u16* Kb = Ks[cur];
        const u16* Vb = Vs[cur];
        const int kv0 = kvb * 64;

        if (kvb < dW) {
            QK1(0, 0);
            QK1(1, 0);
        } else if (kvb == dW) {
            QK1(0, 1);
            QK1(1, 1);
        }

        asm volatile("s_waitcnt vmcnt(0)" ::: "memory");
        __syncthreads();
    }

    float lt = lr + __shfl_xor(lr, 32);
    if (lane < 32) Llds[ww][l31] = lt;
    __syncthreads();
#pragma unroll
    for (int r = 0; r < 16; r++) {
        int qr = (r & 3) + 8 * (r >> 2) + 4 * hi8;
        float linv = 1.0f / Llds[ww][qr];
        u16* op = O + (size_t)(qg0 + qr) * 2048 + h * 128 + l31;
#pragma unroll
        for (int nt = 0; nt < 4; nt++)
            op[nt * 32] = f2bf(acc[nt][r] * linv);
    }
}

// ---------------------------------------------------------------- launch
extern "C" void kernel_launch(void* const* d_in, const int* in_sizes, int n_in,
                              void* d_out, int out_size, void* d_ws, size_t ws_size,
                              hipStream_t stream) {
    const float* hidden = (const float*)d_in[0];
    const float* Wq = (const float*)d_in[1];
    const float* Wk = (const float*)d_in[2];
    const float* Wv = (const float*)d_in[3];
    const float* Wo = (const float*)d_in[4];
    float* out = (float*)d_out;   // reference output dtype is FLOAT32

    u16* ws   = (u16*)d_ws;
    u16* Hb   = ws;                   // 8388608  (hidden bf16; dead after gemm_qkv ->
                                      //           reused as slice-0 partial, then final Ob)
    u16* Qb   = Hb   + 8388608;       // 8388608
    u16* KVb  = Qb   + 8388608;       // 4194304 (K cols 0..511 | V cols 512..1023)
    u16* WqT  = KVb  + 4194304;       // 4194304 (later reused as WoT)
    u16* WkvT = WqT  + 4194304;       // 2097152 (WkT/WvT; dead after gemm_qkv -> l-partials)
    u16* VT   = WkvT + 2097152;       // 4194304 (V^T [512][4096])
    u16* Op1  = VT   + 4194304;       // 8388608 (slice-1 partial O; EXTRA 16.8MB, guarded)
    // base total 60 MB; split-kv path needs 76.8 MB
    const size_t WS_SPLIT = (size_t)(31457280 + 8388608) * 2;  // bytes

    convert_hidden<<<4096, 256, 0, stream>>>(hidden, Hb, 1048576);

    transpose_cvt<<<dim3(32, 32), 256, 0, stream>>>(Wq, WqT, 2048, 2048);
    transpose_cvt<<<dim3(8, 32), 256, 0, stream>>>(Wk, WkvT, 2048, 512);
    transpose_cvt<<<dim3(8, 32), 256, 0, stream>>>(Wv, WkvT + 1048576, 2048, 512);

    gemm_qkv<<<dim3(24, 32), 256, 0, stream>>>(Hb, WqT, WkvT, Qb, KVb);

    // WqT dead -> reuse for WoT
    u16* WoT = WqT;
    transpose_cvt<<<dim3(32, 32), 256, 0, stream>>>(Wo, WoT, 2048, 2048);

    rope_kernel<<<dim3(20480), 256, 0, stream>>>(Qb, KVb);

    // V^T for flash (V = KVb cols 512..1023; untouched by rope)
    transpose_b16<<<dim3(8, 64), 256, 0, stream>>>(KVb, VT, 4096, 512, 1024, 512);

    // Hb dead -> partial-O slice 0 / final Ob
    u16* Ob = Hb;
    if (ws_size >= WS_SPLIT) {
        float* Lp = (float*)WkvT;     // 512 KB within the dead 4 MB region
        flash_attn10<<<dim3(1024), 256, 0, stream>>>(Qb, KVb, VT, Ob, Op1, Lp);
        merge_o<<<dim3(4096), 256, 0, stream>>>(Ob, Op1, Lp);
    } else {
        flash_attn7<<<dim3(512), 256, 0, stream>>>(Qb, KVb, VT, Ob);
    }

    gemm_bt<true><<<dim3(16, 32), 256, 0, stream>>>(Ob, WoT, out, 4096, 2048, 2048);
}

// Round 9
// 379.500 us; speedup vs baseline: 1.0361x; 1.0361x over previous
//
#include <hip/hip_runtime.h>
#include <stdint.h>

typedef uint16_t u16;
typedef __bf16  bf16x8 __attribute__((ext_vector_type(8)));
typedef float   f32x4  __attribute__((ext_vector_type(4)));
typedef float   f32x16 __attribute__((ext_vector_type(16)));
typedef uint16_t u16x8 __attribute__((ext_vector_type(8), may_alias));
typedef uint32_t u32x4 __attribute__((ext_vector_type(4)));

typedef const __attribute__((address_space(1))) void* gas_p;
typedef __attribute__((address_space(3))) void* las_p;

#define SCALE2 0.1275430214486847f   // (1/sqrt(128)) * log2(e)

__device__ __forceinline__ void load_lds16(const void* g, void* l) {
    // async global->LDS DMA, 16B/lane; LDS dest = wave-uniform base + lane*16
    __builtin_amdgcn_global_load_lds((gas_p)g, (las_p)l, 16, 0, 0);
}

__device__ __forceinline__ u16 f2bf(float f) {
    uint32_t u = __builtin_bit_cast(uint32_t, f);
    u += 0x7FFFu + ((u >> 16) & 1u);   // RNE
    return (u16)(u >> 16);
}
__device__ __forceinline__ float bf2f(u16 h) {
    uint32_t u = ((uint32_t)h) << 16;
    return __builtin_bit_cast(float, u);
}
__device__ __forceinline__ bf16x8 ld_frag(const u16* p) {
    u16x8 t = *(const u16x8*)p;
    return __builtin_bit_cast(bf16x8, t);
}
__device__ __forceinline__ uint32_t cvt_pk_bf16(float lo, float hi) {
    uint32_t r;
    asm("v_cvt_pk_bf16_f32 %0, %1, %2" : "=v"(r) : "v"(lo), "v"(hi));
    return r;
}
__device__ __forceinline__ void plane32_swap(uint32_t& a, uint32_t& b) {
    // a' = {a.lo | b.lo}, b' = {a.hi | b.hi} across the lane<32 / lane>=32 split
    asm("v_permlane32_swap_b32 %0, %1" : "+v"(a), "+v"(b));
}

// ---------------------------------------------------------------- prep: hidden convert + Wq/Wk/Wv transposes (fused)
__global__ __launch_bounds__(256) void prep(const float* __restrict__ hidden,
                                            u16* __restrict__ Hb,
                                            const float* __restrict__ Wq,
                                            u16* __restrict__ WqT,
                                            const float* __restrict__ Wk,
                                            const float* __restrict__ Wv,
                                            u16* __restrict__ WkvT) {
    __shared__ u16 tile[64][65];
    const int bid = blockIdx.x;
    const int tx  = threadIdx.x;
    if (bid < 4096) {                       // convert hidden f32 -> bf16 (1M x8)
        int i = bid * 256 + tx;
        const float* p = hidden + (size_t)i * 8;
        u16x8 o;
#pragma unroll
        for (int j = 0; j < 8; j++) o[j] = f2bf(p[j]);
        *(u16x8*)(Hb + (size_t)i * 8) = o;
        return;
    }
    const float* in;
    u16* out;
    int R, C, bx, by;
    if (bid < 5120)      { int l = bid - 4096; in = Wq; out = WqT;            R = 2048; C = 2048; bx = l & 31; by = l >> 5; }
    else if (bid < 5376) { int l = bid - 5120; in = Wk; out = WkvT;           R = 2048; C = 512;  bx = l & 7;  by = l >> 3; }
    else                 { int l = bid - 5376; in = Wv; out = WkvT + 1048576; R = 2048; C = 512;  bx = l & 7;  by = l >> 3; }
    const int bc = bx * 64, br = by * 64;
#pragma unroll
    for (int i = 0; i < 16; i++) {
        int idx = tx + i * 256;
        int r = idx >> 6, c = idx & 63;
        tile[r][c] = f2bf(in[(size_t)(br + r) * C + bc + c]);
    }
    __syncthreads();
#pragma unroll
    for (int i = 0; i < 16; i++) {
        int idx = tx + i * 256;
        int r = idx >> 6, c = idx & 63;
        out[(size_t)(bc + r) * R + br + c] = tile[c][r];
    }
}

// ---------------------------------------------------------------- mid: rope + Wo transpose + V^T transpose (fused)
// Independent work, all post-gemm_qkv: rope touches Q + KV cols 0..511;
// transpose_b16 reads KV cols 512..1023; Wo transpose is disjoint.
__global__ __launch_bounds__(256) void mid(u16* __restrict__ Q,
                                           u16* __restrict__ KV,
                                           const float* __restrict__ Wo,
                                           u16* __restrict__ WoT,
                                           u16* __restrict__ VT) {
    __shared__ u16 tile[64][65];
    const int bid = blockIdx.x;
    const int tx  = threadIdx.x;
    if (bid < 20480) {                      // RoPE in-place (Q pre-scaled by SCALE2)
        int g = bid * 256 + tx;
        int d = g & 63;
        int row = g >> 6;
        int s = row / 20;
        int hh = row - s * 20;
        u16* buf = (hh < 16) ? (Q + (size_t)s * 2048 + hh * 128)
                             : (KV + (size_t)s * 1024 + (hh - 16) * 128);
        float p = (float)s;
        float angle = p * exp2f((float)d * (-19.931568569324174f / 64.0f));
        float sc = (hh < 16) ? SCALE2 : 1.0f;
        float c = cosf(angle) * sc, sn = sinf(angle) * sc;
        float x0 = bf2f(buf[d]), x1 = bf2f(buf[d + 64]);
        buf[d]      = f2bf(x0 * c - x1 * sn);
        buf[d + 64] = f2bf(x1 * c + x0 * sn);
        return;
    }
    if (bid < 21504) {                      // Wo f32 [2048][2048] -> WoT bf16 (transposed)
        int l = bid - 20480;
        int bc = (l & 31) * 64, br = (l >> 5) * 64;
#pragma unroll
        for (int i = 0; i < 16; i++) {
            int idx = tx + i * 256;
            int r = idx >> 6, c = idx & 63;
            tile[r][c] = f2bf(Wo[(size_t)(br + r) * 2048 + bc + c]);
        }
        __syncthreads();
#pragma unroll
        for (int i = 0; i < 16; i++) {
            int idx = tx + i * 256;
            int r = idx >> 6, c = idx & 63;
            WoT[(size_t)(bc + r) * 2048 + br + c] = tile[c][r];
        }
        return;
    }
    {                                       // V^T: KV cols 512..1023 -> VT [512][4096]
        int l = bid - 21504;                // grid 8 x 64
        int bc = (l & 7) * 64, br = (l >> 3) * 64;
#pragma unroll
        for (int i = 0; i < 16; i++) {
            int idx = tx + i * 256;
            int r = idx >> 6, c = idx & 63;
            tile[r][c] = KV[(size_t)(br + r) * 1024 + 512 + bc + c];
        }
        __syncthreads();
#pragma unroll
        for (int i = 0; i < 16; i++) {
            int idx = tx + i * 256;
            int r = idx >> 6, c = idx & 63;
            VT[(size_t)(bc + r) * 4096 + br + c] = tile[c][r];
        }
    }
}

// ---------------------------------------------------------------- GEMM core (m97 structure, BK=64)
// 2 K-steps per barrier pair (32 iters vs 64): halves the per-K barrier+drain
// overhead. BK=64 rows are 128B -> frag reads XOR-swizzle byte bits [6:4] with
// row bits [2:0]; staging pre-swizzles the GLOBAL source so the linear
// global_load_lds dest receives the permuted layout (rule #21: same involution
// on source-permute and read -- the pattern already proven in flash K-staging).
#define TM 128
#define TN 128

// fused QKV projection: A[4096][2048] bf16; n-cols 0..2047 -> Q (WqT), 2048..3071 -> KV (WkvT)
__global__ __launch_bounds__(256) void gemm_qkv(const u16* __restrict__ A,
                                                const u16* __restrict__ WqT,
                                                const u16* __restrict__ WkvT,
                                                u16* __restrict__ Qb,
                                                u16* __restrict__ KVb) {
    __shared__ u16 As[128 * 64];
    __shared__ u16 Bs[128 * 64];
    const int K = 2048;
    const int tid  = threadIdx.x;
    const int wave = tid >> 6;
    const int lane = tid & 63;
    const int l15  = lane & 15;
    const int quad = lane >> 4;
    const int m0 = blockIdx.y * TM;
    const int n0 = blockIdx.x * TN;   // 0..2944
    const u16* Bt;
    u16* C;
    int ldC, cbase;
    if (n0 < 2048) { Bt = WqT + (size_t)n0 * K;          C = Qb;  ldC = 2048; cbase = n0; }
    else           { Bt = WkvT + (size_t)(n0 - 2048) * K; C = KVb; ldC = 1024; cbase = n0 - 2048; }
    const int wm = (wave >> 1) * 64;
    const int wn = (wave & 1) * 64;

    f32x4 acc[4][4] = {};

    const int srow = tid >> 3;        // 0..31
    const int swc  = ((tid & 7) ^ (srow & 7)) * 8;   // pre-swizzled source col
    const u16* Ap[4];
    const u16* Bp[4];
#pragma unroll
    for (int r = 0; r < 4; r++) {
        Ap[r] = A  + (size_t)(m0 + srow + r * 32) * K + swc;
        Bp[r] = Bt + (size_t)(srow + r * 32) * K + swc;
    }
    u16* AsD = As + wave * 512;
    u16* BsD = Bs + wave * 512;

    for (int k0 = 0; k0 < K; k0 += 64) {
#pragma unroll
        for (int r = 0; r < 4; r++) load_lds16(Ap[r] + k0, AsD + r * 2048);
#pragma unroll
        for (int r = 0; r < 4; r++) load_lds16(Bp[r] + k0, BsD + r * 2048);
        __syncthreads();
        bf16x8 af[2][4], bfr[2][4];
        const int sx = (l15 & 7) << 3;
#pragma unroll
        for (int kk = 0; kk < 2; kk++)
#pragma unroll
            for (int i = 0; i < 4; i++) {
                af[kk][i]  = ld_frag(&As[((wm + i * 16 + l15) * 64 + kk * 32 + quad * 8) ^ sx]);
                bfr[kk][i] = ld_frag(&Bs[((wn + i * 16 + l15) * 64 + kk * 32 + quad * 8) ^ sx]);
            }
#pragma unroll
        for (int kk = 0; kk < 2; kk++)
#pragma unroll
            for (int i = 0; i < 4; i++)
#pragma unroll
                for (int j = 0; j < 4; j++)
                    acc[i][j] = __builtin_amdgcn_mfma_f32_16x16x32_bf16(af[kk][i], bfr[kk][j], acc[i][j], 0, 0, 0);
        __syncthreads();
    }
#pragma unroll
    for (int i = 0; i < 4; i++)
#pragma unroll
        for (int j = 0; j < 4; j++)
#pragma unroll
            for (int r = 0; r < 4; r++) {
                int row = m0 + wm + i * 16 + quad * 4 + r;
                int col = cbase + wn + j * 16 + l15;
                C[(size_t)row * ldC + col] = f2bf(acc[i][j][r]);
            }
}

template <bool F32OUT>
__global__ __launch_bounds__(256) void gemm_bt(const u16* __restrict__ A,
                                               const u16* __restrict__ Bt,
                                               void* __restrict__ Cp,
                                               int M, int N, int K) {
    __shared__ u16 As[128 * 64];
    __shared__ u16 Bs[128 * 64];
    const int tid  = threadIdx.x;
    const int wave = tid >> 6;
    const int lane = tid & 63;
    const int l15  = lane & 15;
    const int quad = lane >> 4;
    const int m0 = blockIdx.y * TM;
    const int n0 = blockIdx.x * TN;
    const int wm = (wave >> 1) * 64;
    const int wn = (wave & 1) * 64;

    f32x4 acc[4][4] = {};

    const int srow = tid >> 3;
    const int swc  = ((tid & 7) ^ (srow & 7)) * 8;
    const u16* Ap[4];
    const u16* Bp[4];
#pragma unroll
    for (int r = 0; r < 4; r++) {
        Ap[r] = A  + (size_t)(m0 + srow + r * 32) * K + swc;
        Bp[r] = Bt + (size_t)(n0 + srow + r * 32) * K + swc;
    }
    u16* AsD = As + wave * 512;
    u16* BsD = Bs + wave * 512;

    for (int k0 = 0; k0 < K; k0 += 64) {
#pragma unroll
        for (int r = 0; r < 4; r++) load_lds16(Ap[r] + k0, AsD + r * 2048);
#pragma unroll
        for (int r = 0; r < 4; r++) load_lds16(Bp[r] + k0, BsD + r * 2048);
        __syncthreads();
        bf16x8 af[2][4], bfr[2][4];
        const int sx = (l15 & 7) << 3;
#pragma unroll
        for (int kk = 0; kk < 2; kk++)
#pragma unroll
            for (int i = 0; i < 4; i++) {
                af[kk][i]  = ld_frag(&As[((wm + i * 16 + l15) * 64 + kk * 32 + quad * 8) ^ sx]);
                bfr[kk][i] = ld_frag(&Bs[((wn + i * 16 + l15) * 64 + kk * 32 + quad * 8) ^ sx]);
            }
#pragma unroll
        for (int kk = 0; kk < 2; kk++)
#pragma unroll
            for (int i = 0; i < 4; i++)
#pragma unroll
                for (int j = 0; j < 4; j++)
                    acc[i][j] = __builtin_amdgcn_mfma_f32_16x16x32_bf16(af[kk][i], bfr[kk][j], acc[i][j], 0, 0, 0);
        __syncthreads();
    }
#pragma unroll
    for (int i = 0; i < 4; i++)
#pragma unroll
        for (int j = 0; j < 4; j++)
#pragma unroll
            for (int r = 0; r < 4; r++) {
                int row = m0 + wm + i * 16 + quad * 4 + r;
                int col = n0 + wn + j * 16 + l15;
                if (F32OUT)
                    ((float*)Cp)[(size_t)row * N + col] = acc[i][j][r];
                else
                    ((u16*)Cp)[(size_t)row * N + col] = f2bf(acc[i][j][r]);
            }
}

// ---------------------------------------------------------------- flash attention core (v9 exact)
// swapped QK^T (A=K, B=Q), in-register softmax via cvt_pk+permlane32_swap,
// fixed-reference exp2 (Q pre-scaled in rope), linear V^T tile.
#define QK1(CC, MSK)                                                           \
  do {                                                                         \
    const int krow_ = (CC) * 32 + l31;                                         \
    f32x16 sv_ = {};                                                           \
    _Pragma("unroll")                                                          \
    for (int dk = 0; dk < 8; dk++) {                                           \
      bf16x8 kf = ld_frag(&Kb[krow_ * 128 + (((dk * 2 + hi8) + krow_) & 15) * 8]); \
      sv_ = __builtin_amdgcn_mfma_f32_32x32x16_bf16(kf, qf[dk], sv_, 0, 0, 0); \
    }                                                                          \
    float p_[16]; float rs_ = 0.f;                                             \
    const int kvbs_ = kv0 + (CC) * 32 + 4 * hi8;                               \
    _Pragma("unroll")                                                          \
    for (int r = 0; r < 16; r++) {                                             \
      float pe = exp2f(sv_[r]);                                                \
      if (MSK) { int kvv = kvbs_ + (r & 3) + 8 * (r >> 2);                     \
                 pe = (kvv <= qrow) ? pe : 0.f; }                              \
      p_[r] = pe; rs_ += pe;                                                   \
    }                                                                          \
    lr += rs_;                                                                 \
    uint32_t w0 = cvt_pk_bf16(p_[0], p_[1]);                                   \
    uint32_t w1 = cvt_pk_bf16(p_[2], p_[3]);                                   \
    uint32_t w2 = cvt_pk_bf16(p_[4], p_[5]);                                   \
    uint32_t w3 = cvt_pk_bf16(p_[6], p_[7]);                                   \
    plane32_swap(w0, w2); plane32_swap(w1, w3);                                \
    uint32_t w4 = cvt_pk_bf16(p_[8], p_[9]);                                   \
    uint32_t w5 = cvt_pk_bf16(p_[10], p_[11]);                                 \
    uint32_t w6 = cvt_pk_bf16(p_[12], p_[13]);                                 \
    plane32_swap(w4, w6);                                                      \
    uint32_t w7 = cvt_pk_bf16(p_[14], p_[15]);                                 \
    plane32_swap(w5, w7);                                                      \
    u32x4 a0_ = {w0, w1, w2, w3}, a1_ = {w4, w5, w6, w7};                      \
    bf16x8 pa0_ = __builtin_bit_cast(bf16x8, a0_);                             \
    bf16x8 pa1_ = __builtin_bit_cast(bf16x8, a1_);                             \
    _Pragma("unroll")                                                          \
    for (int ks2 = 0; ks2 < 2; ks2++) {                                        \
      bf16x8 pa_ = ks2 ? pa1_ : pa0_;                                          \
      _Pragma("unroll")                                                        \
      for (int nt = 0; nt < 4; nt++) {                                         \
        const int d_ = nt * 32 + l31;                                          \
        bf16x8 vf = ld_frag(&Vb[d_ * 64 + ((((CC) * 4 + ks2 * 2 + hi8) + d_) & 7) * 8]); \
        acc[nt] = __builtin_amdgcn_mfma_f32_32x32x16_bf16(pa_, vf, acc[nt], 0, 0, 0); \
      }                                                                        \
    }                                                                          \
  } while (0)

// ---------------------------------------------------------------- flash attention v9 (split-kv; 96us verified)
__global__ __launch_bounds__(256, 2) void flash_attn9(const u16* __restrict__ Q,
                                                      const u16* __restrict__ KVb,
                                                      const u16* __restrict__ VT,
                                                      u16* __restrict__ Op0,
                                                      u16* __restrict__ Op1,
                                                      float* __restrict__ Lp) {
    __shared__ u16 Ks[2][8192];       // 2 x 16KB: K tile [64 kv][128 d], 16B chunks swizzled
    __shared__ u16 Vs[2][8192];       // 2 x 16KB: V^T tile [128 d][64 kv], chunks swizzled
    const int tid  = threadIdx.x;
    const int ww   = tid >> 6;
    const int lane = tid & 63;
    const int l31  = lane & 31;
    const int hi8  = lane >> 5;
    const int bid  = blockIdx.x;      // 0..1023
    const int h    = (bid & 7) * 2 + ((bid >> 3) & 1);
    const int rest = bid >> 4;        // 0..63
    const int j    = 31 - (rest >> 1);
    const int s    = rest & 1;
    const int kvh  = h >> 2;
    const int qg0  = j * 128 + ww * 32;   // this wave's 32 q-rows
    const int qrow = qg0 + l31;
    const int dW   = qg0 >> 6;        // diagonal kv-block
    const int kb0  = s * (j + 1);     // slice kv range [kb0, kb1)
    const int kb1  = kb0 + (j + 1);

    bf16x8 qf[8];
    {
        const u16* qp = Q + (size_t)qrow * 2048 + h * 128 + hi8 * 8;
#pragma unroll
        for (int dk = 0; dk < 8; dk++) qf[dk] = ld_frag(qp + dk * 16);
    }

    const u16* srcK[4];
    const u16* srcV[4];
#pragma unroll
    for (int r = 0; r < 4; r++) {
        int p = r * 256 + tid;
        int kv = p >> 4;
        srcK[r] = KVb + (size_t)kv * 1024 + kvh * 128 + ((((p & 15) - kv) & 15) * 8);
        int d = p >> 3;
        srcV[r] = VT + (size_t)(kvh * 128 + d) * 4096 + ((((p & 7) - (d & 7)) & 7) * 8);
    }

    f32x16 acc[4] = {};               // raw O-sum [q][d = nt*32 + l31]
    float lr = 0.f;

#pragma unroll
    for (int r = 0; r < 4; r++) {
        load_lds16(srcK[r] + (size_t)(kb0 * 64) * 1024, &Ks[0][r * 2048 + ww * 512]);
        load_lds16(srcV[r] + kb0 * 64, &Vs[0][r * 2048 + ww * 512]);
    }
    asm volatile("s_waitcnt vmcnt(0)" ::: "memory");
    __syncthreads();

    for (int kvb = kb0; kvb < kb1; kvb++) {
        const int cur = (kvb - kb0) & 1;
        if (kvb + 1 < kb1) {
            const int kvn = (kvb + 1) * 64;
#pragma unroll
            for (int r = 0; r < 4; r++) {
                load_lds16(srcK[r] + (size_t)kvn * 1024, &Ks[cur ^ 1][r * 2048 + ww * 512]);
                load_lds16(srcV[r] + kvn, &Vs[cur ^ 1][r * 2048 + ww * 512]);
            }
        }
        const u16* Kb = Ks[cur];
        const u16* Vb = Vs[cur];
        const int kv0 = kvb * 64;

        if (kvb < dW) {                     // full block, no mask
            QK1(0, 0);
            QK1(1, 0);
        } else if (kvb == dW) {             // diagonal: per-element causal mask
            QK1(0, 1);
            QK1(1, 1);
        }                                   // else: past this wave's diagonal -> idle

        asm volatile("s_waitcnt vmcnt(0)" ::: "memory");
        __syncthreads();
    }

    float lt = lr + __shfl_xor(lr, 32);
    if (lane < 32) Lp[(s * 16 + h) * 4096 + qg0 + l31] = lt;
    u16* Ops = s ? Op1 : Op0;
#pragma unroll
    for (int r = 0; r < 16; r++) {
        int qr = (r & 3) + 8 * (r >> 2) + 4 * hi8;
        u16* op = Ops + (size_t)(qg0 + qr) * 2048 + h * 128 + l31;
#pragma unroll
        for (int nt = 0; nt < 4; nt++)
            op[nt * 32] = f2bf(acc[nt][r]);
    }
}

// ---------------------------------------------------------------- slice merge: O = (O0+O1)/(l0+l1)
__global__ __launch_bounds__(256) void merge_o(u16* __restrict__ o0,
                                               const u16* __restrict__ o1,
                                               const float* __restrict__ Lp) {
    int i = blockIdx.x * 256 + threadIdx.x;       // 1,048,576 threads x 8 elems
    size_t base = (size_t)i * 8;
    int row = (int)(base >> 11);
    int h   = (int)((base >> 7) & 15);
    float inv = 1.0f / (Lp[h * 4096 + row] + Lp[(16 + h) * 4096 + row]);
    u16x8 a = *(const u16x8*)(o0 + base);
    u16x8 b = *(const u16x8*)(o1 + base);
    u16x8 o;
#pragma unroll
    for (int jj = 0; jj < 8; jj++)
        o[jj] = f2bf((bf2f(a[jj]) + bf2f(b[jj])) * inv);
    *(u16x8*)(o0 + base) = o;
}

// ---------------------------------------------------------------- flash attention v7 (fallback,
// used only when the workspace is too small for split-kv partials)
__global__ __launch_bounds__(256, 2) void flash_attn7(const u16* __restrict__ Q,
                                                      const u16* __restrict__ KVb,
                                                      const u16* __restrict__ VT,
                                                      u16* __restrict__ O) {
    __shared__ u16 Ks[2][8192];
    __shared__ u16 Vs[2][8192];
    __shared__ float Llds[4][32];
    const int tid  = threadIdx.x;
    const int ww   = tid >> 6;
    const int lane = tid & 63;
    const int l31  = lane & 31;
    const int hi8  = lane >> 5;
    const int bid  = blockIdx.x;      // 0..511
    const int h    = bid >> 5;
    const int cls  = bid & 31;
    const int bx   = cls >> 1;
    const int z    = cls & 1;
    const int kvh  = h >> 2;
    const int qt0  = z ? (3968 - bx * 128) : (bx * 128);
    const int qg0  = qt0 + ww * 32;
    const int qrow = qg0 + l31;
    const int dW   = qg0 >> 6;
    const int nkv  = (qt0 >> 6) + 2;

    bf16x8 qf[8];
    {
        const u16* qp = Q + (size_t)qrow * 2048 + h * 128 + hi8 * 8;
#pragma unroll
        for (int dk = 0; dk < 8; dk++) qf[dk] = ld_frag(qp + dk * 16);
    }

    const u16* srcK[4];
    const u16* srcV[4];
#pragma unroll
    for (int r = 0; r < 4; r++) {
        int p = r * 256 + tid;
        int kv = p >> 4;
        srcK[r] = KVb + (size_t)kv * 1024 + kvh * 128 + ((((p & 15) - kv) & 15) * 8);
        int d = p >> 3;
        srcV[r] = VT + (size_t)(kvh * 128 + d) * 4096 + ((((p & 7) - (d & 7)) & 7) * 8);
    }

    f32x16 acc[4] = {};
    float lr = 0.f;

#pragma unroll
    for (int r = 0; r < 4; r++) {
        load_lds16(srcK[r], &Ks[0][r * 2048 + ww * 512]);
        load_lds16(srcV[r], &Vs[0][r * 2048 + ww * 512]);
    }
    asm volatile("s_waitcnt vmcnt(0)" ::: "memory");
    __syncthreads();

    for (int kvb = 0; kvb < nkv; kvb++) {
        const int cur = kvb & 1;
        if (kvb + 1 < nkv) {
            const int kvn = (kvb + 1) * 64;
#pragma unroll
            for (int r = 0; r < 4; r++) {
                load_lds16(srcK[r] + (size_t)kvn * 1024, &Ks[cur ^ 1][r * 2048 + ww * 512]);
                load_lds16(srcV[r] + kvn, &Vs[cur ^ 1][r * 2048 + ww * 512]);
            }
        }
        const u16* Kb = Ks[cur];
        const u16* Vb = Vs[cur];
        const int kv0 = kvb * 64;

        if (kvb < dW) {
            QK1(0, 0);
            QK1(1, 0);
        } else if (kvb == dW) {
            QK1(0, 1);
            QK1(1, 1);
        }

        asm volatile("s_waitcnt vmcnt(0)" ::: "memory");
        __syncthreads();
    }

    float lt = lr + __shfl_xor(lr, 32);
    if (lane < 32) Llds[ww][l31] = lt;
    __syncthreads();
#pragma unroll
    for (int r = 0; r < 16; r++) {
        int qr = (r & 3) + 8 * (r >> 2) + 4 * hi8;
        float linv = 1.0f / Llds[ww][qr];
        u16* op = O + (size_t)(qg0 + qr) * 2048 + h * 128 + l31;
#pragma unroll
        for (int nt = 0; nt < 4; nt++)
            op[nt * 32] = f2bf(acc[nt][r] * linv);
    }
}

// ---------------------------------------------------------------- launch
extern "C" void kernel_launch(void* const* d_in, const int* in_sizes, int n_in,
                              void* d_out, int out_size, void* d_ws, size_t ws_size,
                              hipStream_t stream) {
    const float* hidden = (const float*)d_in[0];
    const float* Wq = (const float*)d_in[1];
    const float* Wk = (const float*)d_in[2];
    const float* Wv = (const float*)d_in[3];
    const float* Wo = (const float*)d_in[4];
    float* out = (float*)d_out;   // reference output dtype is FLOAT32

    u16* ws   = (u16*)d_ws;
    u16* Hb   = ws;                   // 8388608  (hidden bf16; dead after gemm_qkv ->
                                      //           reused as slice-0 partial, then final Ob)
    u16* Qb   = Hb   + 8388608;       // 8388608
    u16* KVb  = Qb   + 8388608;       // 4194304 (K cols 0..511 | V cols 512..1023)
    u16* WqT  = KVb  + 4194304;       // 4194304 (later reused as WoT)
    u16* WkvT = WqT  + 4194304;       // 2097152 (WkT/WvT; dead after gemm_qkv -> l-partials)
    u16* VT   = WkvT + 2097152;       // 4194304 (V^T [512][4096])
    u16* Op1  = VT   + 4194304;       // 8388608 (slice-1 partial O; EXTRA 16.8MB, guarded)
    const size_t WS_SPLIT = (size_t)(31457280 + 8388608) * 2;  // bytes

    // prep: convert hidden + Wq/Wk/Wv transposes (one launch)
    prep<<<dim3(5632), 256, 0, stream>>>(hidden, Hb, Wq, WqT, Wk, Wv, WkvT);

    gemm_qkv<<<dim3(24, 32), 256, 0, stream>>>(Hb, WqT, WkvT, Qb, KVb);

    // mid: rope + Wo transpose (WqT dead -> WoT) + V^T transpose (one launch)
    u16* WoT = WqT;
    mid<<<dim3(22016), 256, 0, stream>>>(Qb, KVb, Wo, WoT, VT);

    // Hb dead -> partial-O slice 0 / final Ob
    u16* Ob = Hb;
    if (ws_size >= WS_SPLIT) {
        float* Lp = (float*)WkvT;     // 512 KB within the dead 4 MB region
        flash_attn9<<<dim3(1024), 256, 0, stream>>>(Qb, KVb, VT, Ob, Op1, Lp);
        merge_o<<<dim3(4096), 256, 0, stream>>>(Ob, Op1, Lp);
    } else {
        flash_attn7<<<dim3(512), 256, 0, stream>>>(Qb, KVb, VT, Ob);
    }

    gemm_bt<true><<<dim3(16, 32), 256, 0, stream>>>(Ob, WoT, out, 4096, 2048, 2048);
}